// Round 1
// baseline (786.799 us; speedup 1.0000x reference)
//
#include <hip/hip_runtime.h>
#include <hip/hip_bf16.h>

#define NN 8192
#define MM 64
#define NROWS 4096            // B*C_IN = B*C_OUT = 64*64
static constexpr float TWO_PI = 6.28318530717958647692f;

// ---------------- Kernel A: forward truncated DFT ----------------
// Vhat[b,i,m] = sum_n v[b,i,n] * exp(-2*pi*i*m*n/N),  m = 0..63
// One block per (b,i) row. 256 threads = 4 n-quarters x 64 m-values.
__global__ __launch_bounds__(256) void dft_fwd(const float* __restrict__ v,
                                               float2* __restrict__ vhat) {
    __shared__ float row[NN];          // 32 KiB
    __shared__ float pre[4][MM];
    __shared__ float pim[4][MM];

    const int row_id = blockIdx.x;     // b*64 + i
    const float4* src4 = (const float4*)(v + (size_t)row_id * NN);
    float4* row4 = (float4*)row;
    for (int t = threadIdx.x; t < NN / 4; t += 256) row4[t] = src4[t];
    __syncthreads();

    const int m = threadIdx.x & 63;
    const int g = threadIdx.x >> 6;    // 0..3
    const int n0 = g * 2048;

    // starting angle and per-step increment for this (m, n-range)
    const int k0 = (m * n0) & (NN - 1);
    const float phi   = TWO_PI * (float)k0 / (float)NN;
    const float delta = TWO_PI * (float)m  / (float)NN;
    float s, c, sd, cd;
    sincosf(phi,   &s,  &c);
    sincosf(delta, &sd, &cd);

    float re = 0.f, im = 0.f;
    #pragma unroll 8
    for (int j = 0; j < 2048; ++j) {
        const float x = row[n0 + j];
        re = fmaf(x,  c, re);          // cos term
        im = fmaf(x, -s, im);          // e^{-i t} = cos - i sin
        const float cn = fmaf(c, cd, -s * sd);
        const float sn = fmaf(s, cd,  c * sd);
        c = cn; s = sn;
    }

    pre[g][m] = re;
    pim[g][m] = im;
    __syncthreads();
    if (threadIdx.x < MM) {
        const float r = pre[0][m] + pre[1][m] + pre[2][m] + pre[3][m];
        const float i2 = pim[0][m] + pim[1][m] + pim[2][m] + pim[3][m];
        vhat[(size_t)row_id * MM + m] = make_float2(r, i2);
    }
}

// ---------------- Kernel B: per-frequency complex channel mix ----------------
// Xhat[b,o,m] = sum_i Vhat[b,i,m] * (wr[i,o,m] + i*wi[i,o,m])
// 1024 blocks x 256 threads: block covers (b, 4 o-values), thread = (o_local, m)
__global__ __launch_bounds__(256) void mix(const float2* __restrict__ vhat,
                                           const float* __restrict__ wr,
                                           const float* __restrict__ wi,
                                           float2* __restrict__ xhat) {
    const int m  = threadIdx.x & 63;
    const int ol = threadIdx.x >> 6;               // 0..3
    const int b  = blockIdx.x >> 4;                // 0..63
    const int o  = ((blockIdx.x & 15) << 2) + ol;  // 0..63

    float ar = 0.f, ai = 0.f;
    #pragma unroll 4
    for (int i = 0; i < 64; ++i) {
        const float2 vh = vhat[((size_t)(b * 64 + i)) * MM + m];
        const float wre = wr[((size_t)(i * 64 + o)) * MM + m];
        const float wim = wi[((size_t)(i * 64 + o)) * MM + m];
        ar = fmaf(vh.x, wre, ar);
        ar = fmaf(-vh.y, wim, ar);
        ai = fmaf(vh.x, wim, ai);
        ai = fmaf(vh.y, wre, ai);
    }
    xhat[((size_t)(b * 64 + o)) * MM + m] = make_float2(ar, ai);
}

// ---------------- Kernel C: inverse truncated DFT ----------------
// out[b,o,n] = Xr'[0] + sum_{m=1}^{63} Xr'[m]*cos(2pi m n/N) + Xi'[m]*sin(2pi m n/N)
// with Xr'[0] = Re X0 / N, Xr'[m] = 2/N * Re Xm, Xi'[m] = -2/N * Im Xm
__global__ __launch_bounds__(256) void dft_inv(const float2* __restrict__ xhat,
                                               float* __restrict__ out) {
    __shared__ float xr[MM];
    __shared__ float xi[MM];

    const int row_id = blockIdx.x;     // b*64 + o
    if (threadIdx.x < MM) {
        const float2 X = xhat[(size_t)row_id * MM + threadIdx.x];
        const float scale = 2.f / (float)NN;
        if (threadIdx.x == 0) { xr[0] = X.x / (float)NN; xi[0] = 0.f; }
        else { xr[threadIdx.x] = X.x * scale; xi[threadIdx.x] = -X.y * scale; }
    }
    __syncthreads();

    float* dst = out + (size_t)row_id * NN;
    for (int j = 0; j < 32; ++j) {
        const int n = j * 256 + threadIdx.x;      // coalesced stores
        const float theta = TWO_PI * (float)n / (float)NN;
        float st, ct;
        sincosf(theta, &st, &ct);
        float acc = xr[0];
        float c = ct, s = st;                      // angle for m=1
        #pragma unroll 7
        for (int m = 1; m < MM; ++m) {
            acc = fmaf(xr[m], c, acc);
            acc = fmaf(xi[m], s, acc);
            const float cn = fmaf(c, ct, -s * st);
            const float sn = fmaf(s, ct,  c * st);
            c = cn; s = sn;
        }
        dst[n] = acc;
    }
}

extern "C" void kernel_launch(void* const* d_in, const int* in_sizes, int n_in,
                              void* d_out, int out_size, void* d_ws, size_t ws_size,
                              hipStream_t stream) {
    const float* v  = (const float*)d_in[0];
    const float* wr = (const float*)d_in[1];
    const float* wi = (const float*)d_in[2];
    float* out = (float*)d_out;

    float2* vhat = (float2*)d_ws;                                   // 2 MiB
    float2* xhat = (float2*)((char*)d_ws + (size_t)NROWS * MM * sizeof(float2)); // 2 MiB

    dft_fwd<<<NROWS, 256, 0, stream>>>(v, vhat);
    mix<<<1024, 256, 0, stream>>>(vhat, wr, wi, xhat);
    dft_inv<<<NROWS, 256, 0, stream>>>(xhat, out);
}

// Round 3
// 367.212 us; speedup vs baseline: 2.1426x; 2.1426x over previous
//
#include <hip/hip_runtime.h>
#include <hip/hip_bf16.h>
#include <hip/hip_fp16.h>

#define NN 8192
#define NROWS 4096            // B*C = 64*64
#define KSPLIT 8
#define KCHUNK (NN / KSPLIT)  // 1024
static constexpr float TWO_PI = 6.28318530717958647692f;

typedef __attribute__((ext_vector_type(8))) _Float16 half8;
typedef __attribute__((ext_vector_type(4))) float floatx4;

// ---------------- twiddle generation (all on-device, every launch) -------------
// btF[j][k], j in [0,128): j<64 -> cos(2pi j k/N); j>=64 -> -sin(2pi (j-64) k/N)
// (so GEMM1 col j=m gives Re Vhat, col 64+m gives Im Vhat)
__global__ __launch_bounds__(256) void gen_fwd(_Float16* __restrict__ bt) {
    const int idx = blockIdx.x * 256 + threadIdx.x;   // 128*8192 = 1M threads
    const int j = idx >> 13;
    const int k = idx & (NN - 1);
    const int m = j & 63;
    const int t = (m * k) & (NN - 1);                 // exact mod-N reduction
    float s, c;
    sincosf((float)t * (TWO_PI / (float)NN), &s, &c);
    bt[idx] = (_Float16)((j < 64) ? c : -s);
}

// gt[n][c], c in [0,128): c<64 -> cos(2pi c n/N); c>=64 -> sin(2pi (c-64) n/N)
__global__ __launch_bounds__(256) void gen_inv(_Float16* __restrict__ gt) {
    const int idx = blockIdx.x * 256 + threadIdx.x;   // 8192*128 = 1M threads
    const int n = idx >> 7;
    const int c = idx & 127;
    const int m = c & 63;
    const int t = (m * n) & (NN - 1);
    float s, cc;
    sincosf((float)t * (TWO_PI / (float)NN), &s, &cc);
    gt[idx] = (_Float16)((c < 64) ? cc : s);
}

static __device__ inline half8 cvt8(float4 a, float4 b) {
    half8 h;
    h[0] = (_Float16)a.x; h[1] = (_Float16)a.y; h[2] = (_Float16)a.z; h[3] = (_Float16)a.w;
    h[4] = (_Float16)b.x; h[5] = (_Float16)b.y; h[6] = (_Float16)b.z; h[7] = (_Float16)b.w;
    return h;
}

// ---------------- GEMM1: Vhat_partial = v x btF^T --------------------------------
// grid = 64 Mtiles * KSPLIT blocks, 256 thr = 4 waves; wave owns 16 rows x 128 cols.
// A-frag loaded straight from global fp32 (cvt to f16), B-frags from L2-resident btF.
__global__ __launch_bounds__(256) void gemm_fwd(const float* __restrict__ v,
                                                const _Float16* __restrict__ bt,
                                                float* __restrict__ part) {
    const int wid   = threadIdx.x >> 6;
    const int lane  = threadIdx.x & 63;
    const int l15   = lane & 15;
    const int g     = lane >> 4;               // 0..3 (k-group)
    const int mtile = blockIdx.x >> 3;         // 0..63
    const int s     = blockIdx.x & (KSPLIT - 1);

    const int rowA = mtile * 64 + wid * 16 + l15;
    const int k0   = s * KCHUNK + g * 8;
    const float*    ap = v + (size_t)rowA * NN + k0;
    const _Float16* bp = bt + k0 + (size_t)l15 * NN;   // + jt*16*NN + kk

    floatx4 acc[8] = {};
    for (int kk = 0; kk < KCHUNK; kk += 32) {
        float4 a0 = *(const float4*)(ap + kk);
        float4 a1 = *(const float4*)(ap + kk + 4);
        half8 af = cvt8(a0, a1);
        #pragma unroll
        for (int jt = 0; jt < 8; ++jt) {
            half8 bf = *(const half8*)(bp + (size_t)jt * 16 * NN + kk);
            acc[jt] = __builtin_amdgcn_mfma_f32_16x16x32_f16(af, bf, acc[jt], 0, 0, 0);
        }
    }

    float* pout = part + (size_t)s * NROWS * 128;
    const int prow = mtile * 64 + wid * 16 + g * 4;
    #pragma unroll
    for (int jt = 0; jt < 8; ++jt)
        #pragma unroll
        for (int r = 0; r < 4; ++r)
            pout[(size_t)(prow + r) * 128 + jt * 16 + l15] = acc[jt][r];
}

// ---------------- reduce K-split partials ----------------------------------------
__global__ __launch_bounds__(256) void reduce_part(const float* __restrict__ part,
                                                   float* __restrict__ vhat) {
    const int idx = blockIdx.x * 256 + threadIdx.x;    // 4096*128 = 512K
    float a = 0.f;
    #pragma unroll
    for (int s = 0; s < KSPLIT; ++s) a += part[(size_t)s * NROWS * 128 + idx];
    vhat[idx] = a;
}

// ---------------- mix: per-frequency complex channel mix + irfft scaling --------
// Xc[row][m] = 2/N * Re(Xhat) (m=0: 1/N), Xc[row][64+m] = -2/N * Im(Xhat)
__global__ __launch_bounds__(256) void mix(const float* __restrict__ vhat,
                                           const float* __restrict__ wr,
                                           const float* __restrict__ wi,
                                           _Float16* __restrict__ xc) {
    const int m  = threadIdx.x & 63;
    const int ol = threadIdx.x >> 6;
    const int b  = blockIdx.x >> 4;
    const int o  = ((blockIdx.x & 15) << 2) + ol;

    float ar = 0.f, ai = 0.f;
    #pragma unroll 4
    for (int i = 0; i < 64; ++i) {
        const float* vrow = vhat + (size_t)(b * 64 + i) * 128;
        const float vr = vrow[m];
        const float vi = vrow[64 + m];
        const float wre = wr[((size_t)(i * 64 + o)) * 64 + m];
        const float wim = wi[((size_t)(i * 64 + o)) * 64 + m];
        ar = fmaf(vr, wre, ar);  ar = fmaf(-vi, wim, ar);
        ai = fmaf(vr, wim, ai);  ai = fmaf(vi, wre, ai);
    }
    _Float16* xrow = xc + (size_t)(b * 64 + o) * 128;
    if (m == 0) {
        xrow[0]  = (_Float16)(ar * (1.f / (float)NN));
        xrow[64] = (_Float16)0.f;
    } else {
        xrow[m]      = (_Float16)(ar * (2.f / (float)NN));
        xrow[64 + m] = (_Float16)(-ai * (2.f / (float)NN));
    }
}

// ---------------- GEMM2: out = Xc (4096x128) x G (128x8192) ---------------------
// grid = 256 row-tiles x 32 col-tiles; wave owns 16 rows x 64 cols, K=128.
__global__ __launch_bounds__(256) void gemm_inv(const _Float16* __restrict__ xc,
                                                const _Float16* __restrict__ gt,
                                                float* __restrict__ out) {
    const int wid  = threadIdx.x >> 6;
    const int lane = threadIdx.x & 63;
    const int l15  = lane & 15;
    const int g    = lane >> 4;
    const int mt   = blockIdx.x >> 5;
    const int nt   = blockIdx.x & 31;
    const int row0 = mt * 16;
    const int col0 = nt * 256 + wid * 64;

    half8 af[4];
    const _Float16* ap = xc + (size_t)(row0 + l15) * 128 + g * 8;
    #pragma unroll
    for (int ks = 0; ks < 4; ++ks) af[ks] = *(const half8*)(ap + ks * 32);

    floatx4 acc[4] = {};
    #pragma unroll
    for (int jt = 0; jt < 4; ++jt) {
        const _Float16* gp = gt + (size_t)(col0 + jt * 16 + l15) * 128 + g * 8;
        #pragma unroll
        for (int ks = 0; ks < 4; ++ks) {
            half8 bf = *(const half8*)(gp + ks * 32);
            acc[jt] = __builtin_amdgcn_mfma_f32_16x16x32_f16(af[ks], bf, acc[jt], 0, 0, 0);
        }
    }

    #pragma unroll
    for (int jt = 0; jt < 4; ++jt)
        #pragma unroll
        for (int r = 0; r < 4; ++r)
            out[(size_t)(row0 + g * 4 + r) * NN + col0 + jt * 16 + l15] = acc[jt][r];
}

extern "C" void kernel_launch(void* const* d_in, const int* in_sizes, int n_in,
                              void* d_out, int out_size, void* d_ws, size_t ws_size,
                              hipStream_t stream) {
    const float* v  = (const float*)d_in[0];
    const float* wr = (const float*)d_in[1];
    const float* wi = (const float*)d_in[2];
    float* out = (float*)d_out;

    char* ws = (char*)d_ws;
    _Float16* btF  = (_Float16*)(ws);                               // 2 MiB
    _Float16* gt   = (_Float16*)(ws + (2u << 20));                  // 2 MiB
    float*    part = (float*)   (ws + (4u << 20));                  // 16 MiB
    float*    vhat = (float*)   (ws + (20u << 20));                 // 2 MiB
    _Float16* xc   = (_Float16*)(ws + (22u << 20));                 // 1 MiB

    gen_fwd<<<4096, 256, 0, stream>>>(btF);
    gen_inv<<<4096, 256, 0, stream>>>(gt);
    gemm_fwd<<<64 * KSPLIT, 256, 0, stream>>>(v, btF, part);
    reduce_part<<<2048, 256, 0, stream>>>(part, vhat);
    mix<<<1024, 256, 0, stream>>>(vhat, wr, wi, xc);
    gemm_inv<<<8192, 256, 0, stream>>>(xc, gt, out);
}